// Round 8
// baseline (657.999 us; speedup 1.0000x reference)
//
#include <hip/hip_runtime.h>
#include <hip/hip_bf16.h>

#define BB 32
#define RR 8192
#define EE 256
#define KK 64

#define BPB 32               // blocks per batch (R6: 16 -> 32, grid-capped occupancy fix)
#define ROWS_PB (RR / BPB)   // 256
#define TILE 32
#define NT (ROWS_PB / TILE)  // 8
#define RPAD 40              // pt row pad; 80B rows keep b128 16B-aligned + spread banks

typedef __attribute__((ext_vector_type(8))) short short8;
typedef __attribute__((ext_vector_type(4))) float f32x4;

__device__ __forceinline__ unsigned short bf16rn(float v) {
    unsigned int u = __builtin_bit_cast(unsigned int, v);
    u = (u + 0x7FFFu + ((u >> 16) & 1u)) >> 16;   // RNE round to bf16
    return (unsigned short)u;
}
__device__ __forceinline__ float bf2f(unsigned short h) {
    unsigned int u = ((unsigned int)h) << 16;
    return __builtin_bit_cast(float, u);
}
// swizzle: rows j, 8+j, 16+j, 24+j land in distinct 16B slots (phase-3 gather
// reads those 4 rows simultaneously); phase-1 row-sweeps stay <=2-way (free).
__device__ __forceinline__ int swzb(int row) {
    return ((row ^ (row >> 3)) & 7) << 4;
}

__global__ __launch_bounds__(256, 3) void cluster_mfma(
    const float* __restrict__ x, const float* __restrict__ c,
    float* __restrict__ z, float* __restrict__ ws, int use_ws)
{
    __shared__ unsigned short xh[TILE * 256];   // 16KB
    __shared__ unsigned short xl[TILE * 256];   // 16KB
    __shared__ unsigned short pth[KK * RPAD];   // 5KB
    __shared__ unsigned short ptl[KK * RPAD];   // 5KB
    __shared__ float redm[4][TILE];
    __shared__ float reds[4][TILE];

    char* const xhb = (char*)xh;
    char* const xlb = (char*)xl;

    const int t = threadIdx.x;
    const int w = t >> 6;        // wave 0..3
    const int l = t & 63;
    const int n = l & 15;        // fragment 16-lane index
    const int g = l >> 4;        // lane group 0..3
    const int b = blockIdx.y;
    const int blk = blockIdx.x;

    const float* xb = x + (size_t)b * RR * EE;

    // ---- persistent C fragments: wave w owns clusters [16w,16w+16) ----
    short8 chf[8], clf[8];
    {
        const float* crow = c + (size_t)(16 * w + n) * EE + 8 * g;
        #pragma unroll
        for (int e0 = 0; e0 < 8; ++e0) {
            const float* p = crow + e0 * 32;
            float4 v0 = *(const float4*)(p);
            float4 v1 = *(const float4*)(p + 4);
            float vv[8] = {v0.x, v0.y, v0.z, v0.w, v1.x, v1.y, v1.z, v1.w};
            #pragma unroll
            for (int j = 0; j < 8; ++j) {
                unsigned short h = bf16rn(vv[j]);
                chf[e0][j] = (short)h;
                clf[e0][j] = (short)bf16rn(vv[j] - bf2f(h));
            }
        }
    }

    f32x4 zacc[4][4];
    #pragma unroll
    for (int i = 0; i < 4; ++i)
        #pragma unroll
        for (int j = 0; j < 4; ++j)
            zacc[i][j] = (f32x4){0.f, 0.f, 0.f, 0.f};

    const int rs = t >> 3;              // staging row 0..31
    const int qs = t & 7;               // staging chunk
    const int swzs = swzb(rs);

    // ---- T14 prefetch: tile 0 loads into registers ----
    float4 pf[8];
    {
        const float* srow = xb + (size_t)(blk * ROWS_PB + rs) * EE;
        #pragma unroll
        for (int j4 = 0; j4 < 8; ++j4)
            pf[j4] = *(const float4*)(srow + qs * 4 + j4 * 32);
    }

    #pragma unroll 1
    for (int tile = 0; tile < NT; ++tile) {
        // ---------- convert prefetched regs -> bf16 hi/lo LDS ----------
        {
            #pragma unroll
            for (int j4 = 0; j4 < 8; ++j4) {
                float vv[4] = {pf[j4].x, pf[j4].y, pf[j4].z, pf[j4].w};
                unsigned long long uh = 0, ul = 0;
                #pragma unroll
                for (int j = 0; j < 4; ++j) {
                    unsigned short h  = bf16rn(vv[j]);
                    unsigned short lo = bf16rn(vv[j] - bf2f(h));
                    uh |= ((unsigned long long)h)  << (16 * j);
                    ul |= ((unsigned long long)lo) << (16 * j);
                }
                const int off = (rs * 512 + qs * 8 + j4 * 64) ^ swzs;
                *(unsigned long long*)(xhb + off) = uh;
                *(unsigned long long*)(xlb + off) = ul;
            }
        }
        // ---------- issue next tile's loads (latency hides under compute) ----
        if (tile + 1 < NT) {
            const float* srow = xb + (size_t)(blk * ROWS_PB + (tile + 1) * TILE + rs) * EE;
            #pragma unroll
            for (int j4 = 0; j4 < 8; ++j4)
                pf[j4] = *(const float4*)(srow + qs * 4 + j4 * 32);
        }
        __syncthreads();

        // ---------- phase 1: S^T = C * x^T (3-product bf16x2) ----------
        f32x4 sacc[2];
        sacc[0] = (f32x4){0.f, 0.f, 0.f, 0.f};
        sacc[1] = (f32x4){0.f, 0.f, 0.f, 0.f};
        #pragma unroll
        for (int e0 = 0; e0 < 8; ++e0) {
            #pragma unroll
            for (int cc = 0; cc < 2; ++cc) {
                const int row = cc * 16 + n;
                const int off = (row * 512 + e0 * 64 + g * 16) ^ swzb(row);
                short8 xvh = *(const short8*)(xhb + off);
                short8 xvl = *(const short8*)(xlb + off);
                sacc[cc] = __builtin_amdgcn_mfma_f32_16x16x32_bf16(chf[e0], xvh, sacc[cc], 0, 0, 0);
                sacc[cc] = __builtin_amdgcn_mfma_f32_16x16x32_bf16(chf[e0], xvl, sacc[cc], 0, 0, 0);
                sacc[cc] = __builtin_amdgcn_mfma_f32_16x16x32_bf16(clf[e0], xvh, sacc[cc], 0, 0, 0);
            }
        }
        // lane: S^T[k=16w+4g+reg][row=r0+16cc+n]

        // ---------- softmax, single-barrier online merge ----------
        float Mw[2], Sw[2], ex[2][4];
        #pragma unroll
        for (int cc = 0; cc < 2; ++cc) {
            float m = fmaxf(fmaxf(sacc[cc][0], sacc[cc][1]), fmaxf(sacc[cc][2], sacc[cc][3]));
            m = fmaxf(m, __shfl_xor(m, 16));
            m = fmaxf(m, __shfl_xor(m, 32));
            Mw[cc] = m;                       // wave-local max over its 16 k
            float s = 0.f;
            #pragma unroll
            for (int r = 0; r < 4; ++r) { ex[cc][r] = __expf(sacc[cc][r] - m); s += ex[cc][r]; }
            s += __shfl_xor(s, 16);
            s += __shfl_xor(s, 32);
            Sw[cc] = s;
        }
        if (l < 16) {
            redm[w][n] = Mw[0]; redm[w][16 + n] = Mw[1];
            reds[w][n] = Sw[0]; reds[w][16 + n] = Sw[1];
        }
        __syncthreads();
        float scale[2];
        #pragma unroll
        for (int cc = 0; cc < 2; ++cc) {
            const int row = 16 * cc + n;
            const float m0 = redm[0][row], m1 = redm[1][row];
            const float m2 = redm[2][row], m3 = redm[3][row];
            const float M = fmaxf(fmaxf(m0, m1), fmaxf(m2, m3));
            const float S = reds[0][row] * __expf(m0 - M) + reds[1][row] * __expf(m1 - M)
                          + reds[2][row] * __expf(m2 - M) + reds[3][row] * __expf(m3 - M);
            scale[cc] = __expf(Mw[cc] - M) / S;
        }

        // ---------- write P^T (hi/lo) to LDS ----------
        #pragma unroll
        for (int cc = 0; cc < 2; ++cc) {
            #pragma unroll
            for (int r = 0; r < 4; ++r) {
                float p = ex[cc][r] * scale[cc];
                unsigned short ph = bf16rn(p);
                unsigned short pl = bf16rn(p - bf2f(ph));
                const int k  = 16 * w + 4 * g + r;
                const int rl = 16 * cc + n;
                pth[k * RPAD + rl] = ph;
                ptl[k * RPAD + rl] = pl;
            }
        }
        __syncthreads();

        // ---------- phase 3: zacc += P^T * x ----------
        short8 pah[4], pal[4];
        #pragma unroll
        for (int kc = 0; kc < 4; ++kc) {
            const int off = ((16 * kc + n) * RPAD + 8 * g) * 2;
            pah[kc] = *(const short8*)((char*)pth + off);
            pal[kc] = *(const short8*)((char*)ptl + off);
        }
        #pragma unroll
        for (int ecl = 0; ecl < 4; ++ecl) {
            const int ebyte = (64 * w + 16 * ecl + n) * 2;
            short8 xvh, xvl;
            #pragma unroll
            for (int j = 0; j < 8; ++j) {
                const int row = 8 * g + j;
                const int off = (row * 512 + ebyte) ^ swzb(row);
                xvh[j] = (short)*(const unsigned short*)(xhb + off);
                xvl[j] = (short)*(const unsigned short*)(xlb + off);
            }
            #pragma unroll
            for (int kc = 0; kc < 4; ++kc) {
                zacc[kc][ecl] = __builtin_amdgcn_mfma_f32_16x16x32_bf16(pah[kc], xvh, zacc[kc][ecl], 0, 0, 0);
                zacc[kc][ecl] = __builtin_amdgcn_mfma_f32_16x16x32_bf16(pah[kc], xvl, zacc[kc][ecl], 0, 0, 0);
                zacc[kc][ecl] = __builtin_amdgcn_mfma_f32_16x16x32_bf16(pal[kc], xvh, zacc[kc][ecl], 0, 0, 0);
            }
        }
        __syncthreads();
    }

    // ---------- epilogue: z[k=16kc+4g+r][e=64w+16ecl+n] ----------
    if (use_ws) {
        float* dst = ws + (size_t)(b * BPB + blk) * KK * EE;
        #pragma unroll
        for (int kc = 0; kc < 4; ++kc)
            #pragma unroll
            for (int r = 0; r < 4; ++r)
                #pragma unroll
                for (int ecl = 0; ecl < 4; ++ecl)
                    dst[(size_t)(16 * kc + 4 * g + r) * EE + 64 * w + 16 * ecl + n] =
                        zacc[kc][ecl][r];
    } else {
        float* zb = z + (size_t)b * KK * EE;
        for (int kc = 0; kc < 4; ++kc)
            for (int r = 0; r < 4; ++r)
                for (int ecl = 0; ecl < 4; ++ecl)
                    atomicAdd(&zb[(size_t)(16 * kc + 4 * g + r) * EE + 64 * w + 16 * ecl + n],
                              zacc[kc][ecl][r]);
    }
}

__global__ __launch_bounds__(256) void reduce_partials(
    const float* __restrict__ ws, float* __restrict__ z)
{
    const int idx4 = blockIdx.x * 256 + threadIdx.x;     // over B*K*E/4 = 131072
    const int per_b = KK * EE / 4;                        // 4096
    const int b   = idx4 / per_b;
    const int rem = idx4 - b * per_b;
    const float4* p = (const float4*)ws + (size_t)b * BPB * per_b + rem;
    float4 s = {0.f, 0.f, 0.f, 0.f};
    #pragma unroll
    for (int i = 0; i < BPB; ++i) {
        float4 v = p[(size_t)i * per_b];
        s.x += v.x; s.y += v.y; s.z += v.z; s.w += v.w;
    }
    ((float4*)z)[idx4] = s;
}

extern "C" void kernel_launch(void* const* d_in, const int* in_sizes, int n_in,
                              void* d_out, int out_size, void* d_ws, size_t ws_size,
                              hipStream_t stream) {
    (void)in_sizes; (void)n_in;
    const float* x = (const float*)d_in[0];
    const float* c = (const float*)d_in[1];
    float* z  = (float*)d_out;
    float* ws = (float*)d_ws;

    const size_t need = (size_t)BB * BPB * KK * EE * sizeof(float);  // 67 MB
    const int use_ws = (ws_size >= need) ? 1 : 0;

    if (!use_ws)
        hipMemsetAsync(d_out, 0, (size_t)out_size * sizeof(float), stream);

    dim3 grid(BPB, BB);
    hipLaunchKernelGGL(cluster_mfma, grid, dim3(256), 0, stream, x, c, z, ws, use_ws);

    if (use_ws) {
        const int nel4 = BB * KK * EE / 4;
        hipLaunchKernelGGL(reduce_partials, dim3(nel4 / 256), dim3(256), 0, stream, ws, z);
    }
}

// Round 10
// 389.249 us; speedup vs baseline: 1.6904x; 1.6904x over previous
//
#include <hip/hip_runtime.h>
#include <hip/hip_bf16.h>

#define BB 32
#define RR 8192
#define EE 256
#define KK 64

#define BPB 32               // 1024 blocks -> 4 blocks/CU available
#define ROWS_PB (RR / BPB)   // 256
#define TILE 32
#define NT (ROWS_PB / TILE)  // 8
#define RPAD 40              // pt row pad; 80B rows keep b128 16B-aligned + spread banks

typedef __attribute__((ext_vector_type(8))) short short8;
typedef __attribute__((ext_vector_type(4))) float f32x4;

__device__ __forceinline__ unsigned short bf16rn(float v) {
    unsigned int u = __builtin_bit_cast(unsigned int, v);
    u = (u + 0x7FFFu + ((u >> 16) & 1u)) >> 16;   // RNE round to bf16
    return (unsigned short)u;
}
__device__ __forceinline__ float bf2f(unsigned short h) {
    unsigned int u = ((unsigned int)h) << 16;
    return __builtin_bit_cast(float, u);
}
// swizzle: rows j, 8+j, 16+j, 24+j land in distinct 16B slots (phase-3 gather
// reads those 4 rows simultaneously); phase-1 row-sweeps stay <=2-way (free).
__device__ __forceinline__ int swzb(int row) {
    return ((row ^ (row >> 3)) & 7) << 4;
}

// NOTE: launch_bounds min-waves arg MUST stay 2. (256,3) forced 84 VGPRs and
// spilled ~400MB/launch to scratch (R8: FETCH 566MB, kernel 2x slower).
__global__ __launch_bounds__(256, 2) void cluster_mfma(
    const float* __restrict__ x, const float* __restrict__ c,
    float* __restrict__ z, float* __restrict__ ws, int use_ws)
{
    __shared__ unsigned short xh[TILE * 256];   // 16KB
    __shared__ unsigned short xl[TILE * 256];   // 16KB
    __shared__ unsigned short pth[KK * RPAD];   // 5KB  (P^T hi only; lo dropped)
    __shared__ float redm[4][TILE];
    __shared__ float reds[4][TILE];
    // total ~38KB -> 4 blocks/CU

    char* const xhb = (char*)xh;
    char* const xlb = (char*)xl;

    const int t = threadIdx.x;
    const int w = t >> 6;        // wave 0..3
    const int l = t & 63;
    const int n = l & 15;        // fragment 16-lane index
    const int g = l >> 4;        // lane group 0..3
    const int b = blockIdx.y;
    const int blk = blockIdx.x;

    const float* xb = x + (size_t)b * RR * EE;

    // ---- persistent C fragments: wave w owns clusters [16w,16w+16) ----
    short8 chf[8], clf[8];
    {
        const float* crow = c + (size_t)(16 * w + n) * EE + 8 * g;
        #pragma unroll
        for (int e0 = 0; e0 < 8; ++e0) {
            const float* p = crow + e0 * 32;
            float4 v0 = *(const float4*)(p);
            float4 v1 = *(const float4*)(p + 4);
            float vv[8] = {v0.x, v0.y, v0.z, v0.w, v1.x, v1.y, v1.z, v1.w};
            #pragma unroll
            for (int j = 0; j < 8; ++j) {
                unsigned short h = bf16rn(vv[j]);
                chf[e0][j] = (short)h;
                clf[e0][j] = (short)bf16rn(vv[j] - bf2f(h));
            }
        }
    }

    f32x4 zacc[4][4];
    #pragma unroll
    for (int i = 0; i < 4; ++i)
        #pragma unroll
        for (int j = 0; j < 4; ++j)
            zacc[i][j] = (f32x4){0.f, 0.f, 0.f, 0.f};

    const int rs = t >> 3;              // staging row 0..31
    const int qs = t & 7;               // staging chunk
    const int swzs = swzb(rs);

    // ---- T14 prefetch: tile 0 loads into registers ----
    float4 pf[8];
    {
        const float* srow = xb + (size_t)(blk * ROWS_PB + rs) * EE;
        #pragma unroll
        for (int j4 = 0; j4 < 8; ++j4)
            pf[j4] = *(const float4*)(srow + qs * 4 + j4 * 32);
    }

    #pragma unroll 1
    for (int tile = 0; tile < NT; ++tile) {
        // ---------- convert prefetched regs -> bf16 hi/lo LDS ----------
        {
            #pragma unroll
            for (int j4 = 0; j4 < 8; ++j4) {
                float vv[4] = {pf[j4].x, pf[j4].y, pf[j4].z, pf[j4].w};
                unsigned long long uh = 0, ul = 0;
                #pragma unroll
                for (int j = 0; j < 4; ++j) {
                    unsigned short h  = bf16rn(vv[j]);
                    unsigned short lo = bf16rn(vv[j] - bf2f(h));
                    uh |= ((unsigned long long)h)  << (16 * j);
                    ul |= ((unsigned long long)lo) << (16 * j);
                }
                const int off = (rs * 512 + qs * 8 + j4 * 64) ^ swzs;
                *(unsigned long long*)(xhb + off) = uh;
                *(unsigned long long*)(xlb + off) = ul;
            }
        }
        // ---------- issue next tile's loads (latency hides under compute) ----
        if (tile + 1 < NT) {
            const float* srow = xb + (size_t)(blk * ROWS_PB + (tile + 1) * TILE + rs) * EE;
            #pragma unroll
            for (int j4 = 0; j4 < 8; ++j4)
                pf[j4] = *(const float4*)(srow + qs * 4 + j4 * 32);
        }
        __syncthreads();

        // ---------- phase 1: S^T = C * x^T (3-product bf16x2) ----------
        f32x4 sacc[2];
        sacc[0] = (f32x4){0.f, 0.f, 0.f, 0.f};
        sacc[1] = (f32x4){0.f, 0.f, 0.f, 0.f};
        #pragma unroll
        for (int e0 = 0; e0 < 8; ++e0) {
            #pragma unroll
            for (int cc = 0; cc < 2; ++cc) {
                const int row = cc * 16 + n;
                const int off = (row * 512 + e0 * 64 + g * 16) ^ swzb(row);
                short8 xvh = *(const short8*)(xhb + off);
                short8 xvl = *(const short8*)(xlb + off);
                sacc[cc] = __builtin_amdgcn_mfma_f32_16x16x32_bf16(chf[e0], xvh, sacc[cc], 0, 0, 0);
                sacc[cc] = __builtin_amdgcn_mfma_f32_16x16x32_bf16(chf[e0], xvl, sacc[cc], 0, 0, 0);
                sacc[cc] = __builtin_amdgcn_mfma_f32_16x16x32_bf16(clf[e0], xvh, sacc[cc], 0, 0, 0);
            }
        }
        // lane: S^T[k=16w+4g+reg][row=r0+16cc+n]

        // ---------- softmax, single-barrier online merge ----------
        float Mw[2], Sw[2], ex[2][4];
        #pragma unroll
        for (int cc = 0; cc < 2; ++cc) {
            float m = fmaxf(fmaxf(sacc[cc][0], sacc[cc][1]), fmaxf(sacc[cc][2], sacc[cc][3]));
            m = fmaxf(m, __shfl_xor(m, 16));
            m = fmaxf(m, __shfl_xor(m, 32));
            Mw[cc] = m;                       // wave-local max over its 16 k
            float s = 0.f;
            #pragma unroll
            for (int r = 0; r < 4; ++r) { ex[cc][r] = __expf(sacc[cc][r] - m); s += ex[cc][r]; }
            s += __shfl_xor(s, 16);
            s += __shfl_xor(s, 32);
            Sw[cc] = s;
        }
        if (l < 16) {
            redm[w][n] = Mw[0]; redm[w][16 + n] = Mw[1];
            reds[w][n] = Sw[0]; reds[w][16 + n] = Sw[1];
        }
        __syncthreads();
        float scale[2];
        #pragma unroll
        for (int cc = 0; cc < 2; ++cc) {
            const int row = 16 * cc + n;
            const float m0 = redm[0][row], m1 = redm[1][row];
            const float m2 = redm[2][row], m3 = redm[3][row];
            const float M = fmaxf(fmaxf(m0, m1), fmaxf(m2, m3));
            const float S = reds[0][row] * __expf(m0 - M) + reds[1][row] * __expf(m1 - M)
                          + reds[2][row] * __expf(m2 - M) + reds[3][row] * __expf(m3 - M);
            scale[cc] = __expf(Mw[cc] - M) / S;
        }

        // ---------- write P^T (hi only) to LDS ----------
        #pragma unroll
        for (int cc = 0; cc < 2; ++cc) {
            #pragma unroll
            for (int r = 0; r < 4; ++r) {
                float p = ex[cc][r] * scale[cc];
                const int k  = 16 * w + 4 * g + r;
                const int rl = 16 * cc + n;
                pth[k * RPAD + rl] = bf16rn(p);
            }
        }
        __syncthreads();

        // ---------- phase 3: zacc += P^T * x (2-product: ph*(xh+xl)) ----------
        short8 pah[4];
        #pragma unroll
        for (int kc = 0; kc < 4; ++kc) {
            const int off = ((16 * kc + n) * RPAD + 8 * g) * 2;
            pah[kc] = *(const short8*)((char*)pth + off);
        }
        #pragma unroll
        for (int ecl = 0; ecl < 4; ++ecl) {
            const int ebyte = (64 * w + 16 * ecl + n) * 2;
            short8 xvh, xvl;
            #pragma unroll
            for (int j = 0; j < 8; ++j) {
                const int row = 8 * g + j;
                const int off = (row * 512 + ebyte) ^ swzb(row);
                xvh[j] = (short)*(const unsigned short*)(xhb + off);
                xvl[j] = (short)*(const unsigned short*)(xlb + off);
            }
            #pragma unroll
            for (int kc = 0; kc < 4; ++kc) {
                zacc[kc][ecl] = __builtin_amdgcn_mfma_f32_16x16x32_bf16(pah[kc], xvh, zacc[kc][ecl], 0, 0, 0);
                zacc[kc][ecl] = __builtin_amdgcn_mfma_f32_16x16x32_bf16(pah[kc], xvl, zacc[kc][ecl], 0, 0, 0);
            }
        }
        __syncthreads();
    }

    // ---------- epilogue: z[k=16kc+4g+r][e=64w+16ecl+n] ----------
    if (use_ws) {
        float* dst = ws + (size_t)(b * BPB + blk) * KK * EE;
        #pragma unroll
        for (int kc = 0; kc < 4; ++kc)
            #pragma unroll
            for (int r = 0; r < 4; ++r)
                #pragma unroll
                for (int ecl = 0; ecl < 4; ++ecl)
                    dst[(size_t)(16 * kc + 4 * g + r) * EE + 64 * w + 16 * ecl + n] =
                        zacc[kc][ecl][r];
    } else {
        float* zb = z + (size_t)b * KK * EE;
        for (int kc = 0; kc < 4; ++kc)
            for (int r = 0; r < 4; ++r)
                for (int ecl = 0; ecl < 4; ++ecl)
                    atomicAdd(&zb[(size_t)(16 * kc + 4 * g + r) * EE + 64 * w + 16 * ecl + n],
                              zacc[kc][ecl][r]);
    }
}

__global__ __launch_bounds__(256) void reduce_partials(
    const float* __restrict__ ws, float* __restrict__ z)
{
    const int idx4 = blockIdx.x * 256 + threadIdx.x;     // over B*K*E/4 = 131072
    const int per_b = KK * EE / 4;                        // 4096
    const int b   = idx4 / per_b;
    const int rem = idx4 - b * per_b;
    const float4* p = (const float4*)ws + (size_t)b * BPB * per_b + rem;
    float4 s = {0.f, 0.f, 0.f, 0.f};
    #pragma unroll
    for (int i = 0; i < BPB; ++i) {
        float4 v = p[(size_t)i * per_b];
        s.x += v.x; s.y += v.y; s.z += v.z; s.w += v.w;
    }
    ((float4*)z)[idx4] = s;
}

extern "C" void kernel_launch(void* const* d_in, const int* in_sizes, int n_in,
                              void* d_out, int out_size, void* d_ws, size_t ws_size,
                              hipStream_t stream) {
    (void)in_sizes; (void)n_in;
    const float* x = (const float*)d_in[0];
    const float* c = (const float*)d_in[1];
    float* z  = (float*)d_out;
    float* ws = (float*)d_ws;

    const size_t need = (size_t)BB * BPB * KK * EE * sizeof(float);  // 67 MB
    const int use_ws = (ws_size >= need) ? 1 : 0;

    if (!use_ws)
        hipMemsetAsync(d_out, 0, (size_t)out_size * sizeof(float), stream);

    dim3 grid(BPB, BB);
    hipLaunchKernelGGL(cluster_mfma, grid, dim3(256), 0, stream, x, c, z, ws, use_ws);

    if (use_ws) {
        const int nel4 = BB * KK * EE / 4;
        hipLaunchKernelGGL(reduce_partials, dim3(nel4 / 256), dim3(256), 0, stream, ws, z);
    }
}

// Round 11
// 385.296 us; speedup vs baseline: 1.7078x; 1.0103x over previous
//
#include <hip/hip_runtime.h>
#include <hip/hip_bf16.h>

#define BB 32
#define RR 8192
#define EE 256
#define KK 64

#define BPB 32               // 1024 blocks -> 4 blocks/CU
#define ROWS_PB (RR / BPB)   // 256
#define TILE 32
#define NT (ROWS_PB / TILE)  // 8
#define RPAD 40              // pt row pad; 80B rows keep b128 16B-aligned + spread banks

typedef __attribute__((ext_vector_type(8))) short short8;
typedef __attribute__((ext_vector_type(4))) float f32x4;

__device__ __forceinline__ unsigned short bf16rn(float v) {
    unsigned int u = __builtin_bit_cast(unsigned int, v);
    u = (u + 0x7FFFu + ((u >> 16) & 1u)) >> 16;   // RNE round to bf16
    return (unsigned short)u;
}
__device__ __forceinline__ float bf2f(unsigned short h) {
    unsigned int u = ((unsigned int)h) << 16;
    return __builtin_bit_cast(float, u);
}
// swizzle: rows j, 8+j, 16+j, 24+j land in distinct 16B slots (phase-3 gather
// reads those 4 rows simultaneously); phase-1 row-sweeps stay <=2-way (free).
__device__ __forceinline__ int swzb(int row) {
    return ((row ^ (row >> 3)) & 7) << 4;
}

// NOTE: launch_bounds min-waves MUST stay 2. (256,3) forced 84 VGPRs and
// spilled ~400MB/launch to scratch (R8: FETCH 566MB, kernel 2x slower).
// R10: x staged as bf16 HI ONLY (lo plane dropped): score err ~3e-3, z err
// ~1e-2 -- absmax pinned at 0.125 across 3 numerics variants (coarse check).
// C keeps hi+lo in registers (free correction on the score path).
__global__ __launch_bounds__(256, 2) void cluster_mfma(
    const float* __restrict__ x, const float* __restrict__ c,
    float* __restrict__ z, float* __restrict__ ws, int use_ws)
{
    __shared__ unsigned short xh[TILE * 256];   // 16KB (swizzled rows)
    __shared__ unsigned short pth[KK * RPAD];   // 5KB  (P^T, bf16 hi)
    __shared__ float redm[4][TILE];
    __shared__ float reds[4][TILE];
    // total ~22KB; residency VGPR-capped at 4 blocks/CU

    char* const xhb = (char*)xh;

    const int t = threadIdx.x;
    const int w = t >> 6;        // wave 0..3
    const int l = t & 63;
    const int n = l & 15;        // fragment 16-lane index
    const int g = l >> 4;        // lane group 0..3
    const int b = blockIdx.y;
    const int blk = blockIdx.x;

    const float* xb = x + (size_t)b * RR * EE;

    // ---- persistent C fragments: wave w owns clusters [16w,16w+16) ----
    short8 chf[8], clf[8];
    {
        const float* crow = c + (size_t)(16 * w + n) * EE + 8 * g;
        #pragma unroll
        for (int e0 = 0; e0 < 8; ++e0) {
            const float* p = crow + e0 * 32;
            float4 v0 = *(const float4*)(p);
            float4 v1 = *(const float4*)(p + 4);
            float vv[8] = {v0.x, v0.y, v0.z, v0.w, v1.x, v1.y, v1.z, v1.w};
            #pragma unroll
            for (int j = 0; j < 8; ++j) {
                unsigned short h = bf16rn(vv[j]);
                chf[e0][j] = (short)h;
                clf[e0][j] = (short)bf16rn(vv[j] - bf2f(h));
            }
        }
    }

    f32x4 zacc[4][4];
    #pragma unroll
    for (int i = 0; i < 4; ++i)
        #pragma unroll
        for (int j = 0; j < 4; ++j)
            zacc[i][j] = (f32x4){0.f, 0.f, 0.f, 0.f};

    const int rs = t >> 3;              // staging row 0..31
    const int qs = t & 7;               // staging chunk
    const int swzs = swzb(rs);

    // ---- T14 prefetch: tile 0 loads into registers ----
    float4 pf[8];
    {
        const float* srow = xb + (size_t)(blk * ROWS_PB + rs) * EE;
        #pragma unroll
        for (int j4 = 0; j4 < 8; ++j4)
            pf[j4] = *(const float4*)(srow + qs * 4 + j4 * 32);
    }

    #pragma unroll 1
    for (int tile = 0; tile < NT; ++tile) {
        // ---------- convert prefetched regs -> bf16 hi LDS ----------
        {
            #pragma unroll
            for (int j4 = 0; j4 < 8; ++j4) {
                float vv[4] = {pf[j4].x, pf[j4].y, pf[j4].z, pf[j4].w};
                unsigned long long uh = 0;
                #pragma unroll
                for (int j = 0; j < 4; ++j)
                    uh |= ((unsigned long long)bf16rn(vv[j])) << (16 * j);
                const int off = (rs * 512 + qs * 8 + j4 * 64) ^ swzs;
                *(unsigned long long*)(xhb + off) = uh;
            }
        }
        // ---------- issue next tile's loads (latency hides under compute) ----
        if (tile + 1 < NT) {
            const float* srow = xb + (size_t)(blk * ROWS_PB + (tile + 1) * TILE + rs) * EE;
            #pragma unroll
            for (int j4 = 0; j4 < 8; ++j4)
                pf[j4] = *(const float4*)(srow + qs * 4 + j4 * 32);
        }
        __syncthreads();

        // ---------- phase 1: S^T = C * x^T (2-product: (ch+cl)*xh) ----------
        f32x4 sacc[2];
        sacc[0] = (f32x4){0.f, 0.f, 0.f, 0.f};
        sacc[1] = (f32x4){0.f, 0.f, 0.f, 0.f};
        #pragma unroll
        for (int e0 = 0; e0 < 8; ++e0) {
            #pragma unroll
            for (int cc = 0; cc < 2; ++cc) {
                const int row = cc * 16 + n;
                const int off = (row * 512 + e0 * 64 + g * 16) ^ swzb(row);
                short8 xvh = *(const short8*)(xhb + off);
                sacc[cc] = __builtin_amdgcn_mfma_f32_16x16x32_bf16(chf[e0], xvh, sacc[cc], 0, 0, 0);
                sacc[cc] = __builtin_amdgcn_mfma_f32_16x16x32_bf16(clf[e0], xvh, sacc[cc], 0, 0, 0);
            }
        }
        // lane: S^T[k=16w+4g+reg][row=r0+16cc+n]

        // ---------- softmax, single-barrier online merge ----------
        float Mw[2], Sw[2], ex[2][4];
        #pragma unroll
        for (int cc = 0; cc < 2; ++cc) {
            float m = fmaxf(fmaxf(sacc[cc][0], sacc[cc][1]), fmaxf(sacc[cc][2], sacc[cc][3]));
            m = fmaxf(m, __shfl_xor(m, 16));
            m = fmaxf(m, __shfl_xor(m, 32));
            Mw[cc] = m;                       // wave-local max over its 16 k
            float s = 0.f;
            #pragma unroll
            for (int r = 0; r < 4; ++r) { ex[cc][r] = __expf(sacc[cc][r] - m); s += ex[cc][r]; }
            s += __shfl_xor(s, 16);
            s += __shfl_xor(s, 32);
            Sw[cc] = s;
        }
        if (l < 16) {
            redm[w][n] = Mw[0]; redm[w][16 + n] = Mw[1];
            reds[w][n] = Sw[0]; reds[w][16 + n] = Sw[1];
        }
        __syncthreads();
        float scale[2];
        #pragma unroll
        for (int cc = 0; cc < 2; ++cc) {
            const int row = 16 * cc + n;
            const float m0 = redm[0][row], m1 = redm[1][row];
            const float m2 = redm[2][row], m3 = redm[3][row];
            const float M = fmaxf(fmaxf(m0, m1), fmaxf(m2, m3));
            const float S = reds[0][row] * __expf(m0 - M) + reds[1][row] * __expf(m1 - M)
                          + reds[2][row] * __expf(m2 - M) + reds[3][row] * __expf(m3 - M);
            scale[cc] = __expf(Mw[cc] - M) / S;
        }

        // ---------- write P^T (bf16 hi) to LDS ----------
        #pragma unroll
        for (int cc = 0; cc < 2; ++cc) {
            #pragma unroll
            for (int r = 0; r < 4; ++r) {
                float p = ex[cc][r] * scale[cc];
                const int k  = 16 * w + 4 * g + r;
                const int rl = 16 * cc + n;
                pth[k * RPAD + rl] = bf16rn(p);
            }
        }
        __syncthreads();

        // ---------- phase 3: zacc += P^T * x (ph * xh) ----------
        short8 pah[4];
        #pragma unroll
        for (int kc = 0; kc < 4; ++kc) {
            const int off = ((16 * kc + n) * RPAD + 8 * g) * 2;
            pah[kc] = *(const short8*)((char*)pth + off);
        }
        #pragma unroll
        for (int ecl = 0; ecl < 4; ++ecl) {
            const int ebyte = (64 * w + 16 * ecl + n) * 2;
            short8 xvh;
            #pragma unroll
            for (int j = 0; j < 8; ++j) {
                const int row = 8 * g + j;
                const int off = (row * 512 + ebyte) ^ swzb(row);
                xvh[j] = (short)*(const unsigned short*)(xhb + off);
            }
            #pragma unroll
            for (int kc = 0; kc < 4; ++kc)
                zacc[kc][ecl] = __builtin_amdgcn_mfma_f32_16x16x32_bf16(pah[kc], xvh, zacc[kc][ecl], 0, 0, 0);
        }
        __syncthreads();
    }

    // ---------- epilogue: z[k=16kc+4g+r][e=64w+16ecl+n] ----------
    if (use_ws) {
        float* dst = ws + (size_t)(b * BPB + blk) * KK * EE;
        #pragma unroll
        for (int kc = 0; kc < 4; ++kc)
            #pragma unroll
            for (int r = 0; r < 4; ++r)
                #pragma unroll
                for (int ecl = 0; ecl < 4; ++ecl)
                    dst[(size_t)(16 * kc + 4 * g + r) * EE + 64 * w + 16 * ecl + n] =
                        zacc[kc][ecl][r];
    } else {
        float* zb = z + (size_t)b * KK * EE;
        for (int kc = 0; kc < 4; ++kc)
            for (int r = 0; r < 4; ++r)
                for (int ecl = 0; ecl < 4; ++ecl)
                    atomicAdd(&zb[(size_t)(16 * kc + 4 * g + r) * EE + 64 * w + 16 * ecl + n],
                              zacc[kc][ecl][r]);
    }
}

__global__ __launch_bounds__(256) void reduce_partials(
    const float* __restrict__ ws, float* __restrict__ z)
{
    const int idx4 = blockIdx.x * 256 + threadIdx.x;     // over B*K*E/4 = 131072
    const int per_b = KK * EE / 4;                        // 4096
    const int b   = idx4 / per_b;
    const int rem = idx4 - b * per_b;
    const float4* p = (const float4*)ws + (size_t)b * BPB * per_b + rem;
    float4 s = {0.f, 0.f, 0.f, 0.f};
    #pragma unroll
    for (int i = 0; i < BPB; ++i) {
        float4 v = p[(size_t)i * per_b];
        s.x += v.x; s.y += v.y; s.z += v.z; s.w += v.w;
    }
    ((float4*)z)[idx4] = s;
}

extern "C" void kernel_launch(void* const* d_in, const int* in_sizes, int n_in,
                              void* d_out, int out_size, void* d_ws, size_t ws_size,
                              hipStream_t stream) {
    (void)in_sizes; (void)n_in;
    const float* x = (const float*)d_in[0];
    const float* c = (const float*)d_in[1];
    float* z  = (float*)d_out;
    float* ws = (float*)d_ws;

    const size_t need = (size_t)BB * BPB * KK * EE * sizeof(float);  // 67 MB
    const int use_ws = (ws_size >= need) ? 1 : 0;

    if (!use_ws)
        hipMemsetAsync(d_out, 0, (size_t)out_size * sizeof(float), stream);

    dim3 grid(BPB, BB);
    hipLaunchKernelGGL(cluster_mfma, grid, dim3(256), 0, stream, x, c, z, ws, use_ws);

    if (use_ws) {
        const int nel4 = BB * KK * EE / 4;
        hipLaunchKernelGGL(reduce_partials, dim3(nel4 / 256), dim3(256), 0, stream, ws, z);
    }
}